// Round 2
// baseline (598.904 us; speedup 1.0000x reference)
//
#include <hip/hip_runtime.h>
#include <math.h>

#define BB 256
#define TT 512
#define KK 128
#define AIDX(i) ((i) + (((i) >> 5) << 2))

typedef float v2f __attribute__((ext_vector_type(2)));
typedef unsigned short u16v2 __attribute__((ext_vector_type(2)));

template<int CTRL>
__device__ __forceinline__ int dpp_i(int x) {
  return __builtin_amdgcn_update_dpp(x, x, CTRL, 0xF, 0xF, true);
}
template<int CTRL>
__device__ __forceinline__ float dpp_f(float x) {
  return __int_as_float(dpp_i<CTRL>(__float_as_int(x)));
}
__device__ __forceinline__ float swz16_f(float x) {
  return __int_as_float(__builtin_amdgcn_ds_swizzle(__float_as_int(x), 0x401F));
}
__device__ __forceinline__ int pkminu16(int a, int b) {
  u16v2 av = *(u16v2*)&a, bv = *(u16v2*)&b;
  u16v2 r = __builtin_elementwise_min(av, bv);
  return *(int*)&r;
}
// barrier that drains LDS only (not vmcnt) — keeps prefetch loads in flight
#define BARRIER_LGKM() asm volatile("s_waitcnt lgkmcnt(0)\ns_barrier" ::: "memory")

// DPP: 0xB1 quad_perm xor1, 0x4E quad_perm xor2, 0x141 row_half_mirror
// (acts as xor4 once values are quad-uniform), 0x140 row_mirror (xor8 when 8-uniform)

// MERGED kernel: one block per batch item runs BOTH the viterbi recursion and
// the forward (log-norm) recursion. Same L, same emissions, one barrier per
// timestep serves both; the two independent dependency chains fill each
// other's latency bubbles. Grid = 256 blocks = 1 block/CU.
__global__ __launch_bounds__(512, 2) void crf_main(
    const float* __restrict__ logits,     // [B,T,K]
    const int* __restrict__ labels,       // [B,T]
    const int* __restrict__ seq_lens,     // [B]
    const float* __restrict__ trans,      // [K,K]
    float* __restrict__ pred_out,         // [B,T] as float (d_out+1)
    float* __restrict__ negll,            // [B] in ws
    unsigned char* __restrict__ bp)       // [B][128 chunk][64 cg][8B] in ws
{
  const int tid = threadIdx.x;
  const int cg = tid >> 3, rg = tid & 7;
  const int j0 = cg * 2, i0 = rg * 16;
  const int b = blockIdx.x;
  const int L = seq_lens[b];

  __shared__ __align__(16) float av[2][144];    // viterbi alpha (log domain)
  __shared__ __align__(16) float evs[2][144];   // forward alpha (exp domain)
  __shared__ __align__(16) float wmax[16];
  __shared__ unsigned char tags[TT];
  __shared__ float rv[8]; __shared__ int ri[8];
  __shared__ float rs[8]; __shared__ float rsc[8];
  __shared__ int last_s;

  // transition registers for both paths (raw + exp)
  v2f tv[16], tw[16];
#pragma unroll
  for (int ii = 0; ii < 16; ++ii) {
    v2f tr = *(const v2f*)&trans[(i0 + ii) * KK + j0];
    tv[ii] = tr;
    tw[ii].x = __expf(tr.x);
    tw[ii].y = __expf(tr.y);
  }

  if (tid < KK) {
    float l0 = logits[(b * TT) * KK + tid];
    av[0][AIDX(tid)] = l0;
    evs[0][AIDX(tid)] = __expf(l0);
  }
  if (tid < 16) wmax[tid] = 1.0f;

  // one emission prefetch stream serves BOTH recursions
  v2f emC[4], emN[4];
#pragma unroll
  for (int s = 0; s < 4; ++s) {
    int t2 = 1 + s; if (t2 > L - 1) t2 = (L > 1) ? (L - 1) : 0;
    emC[s] = *(const v2f*)&logits[(b * TT + t2) * KK + j0];
  }
  __syncthreads();

  unsigned int pw0 = 0, pw1 = 0; int pend_c = -1;
  float Cln = 0.0f;

  for (int tc = 1; tc < L; tc += 4) {
#pragma unroll
    for (int s = 0; s < 4; ++s) {
      int t2 = tc + 4 + s; if (t2 > L - 1) t2 = L - 1;
      emN[s] = *(const v2f*)&logits[(b * TT + t2) * KK + j0];
    }
    if (pend_c >= 0 && rg == 1) {
      *(uint2*)(bp + (((b << 7) + pend_c) << 9) + (cg << 3)) =
          make_uint2(pw0, pw1);
    }
    // renorm factor (exact pow2), once per 4-step chunk (forward path)
    float r;
    {
      float4 q0 = *(const float4*)&wmax[0];
      float4 q1 = *(const float4*)&wmax[4];
      float4 q2 = *(const float4*)&wmax[8];
      float4 q3 = *(const float4*)&wmax[12];
      float U = fmaxf(fmaxf(fmaxf(q0.x, q0.y), fmaxf(q0.z, q0.w)),
                      fmaxf(fmaxf(q1.x, q1.y), fmaxf(q1.z, q1.w)));
      U = fmaxf(U, fmaxf(fmaxf(fmaxf(q2.x, q2.y), fmaxf(q2.z, q2.w)),
                         fmaxf(fmaxf(q3.x, q3.y), fmaxf(q3.z, q3.w))));
      int ex = (__float_as_int(U) >> 23) & 255;
      r = __int_as_float((254 - ex) << 23);
      Cln += (float)(ex - 127) * 0.6931471805599453f;
    }
    unsigned int w0p = 0, w1p = 0;
#pragma unroll
    for (int s = 0; s < 4; ++s) {
      const int t = tc + s;
      if (t >= L) break;
      // issue both LDS read sets up front (latency overlap)
      const float4* avr = (const float4*)(av[(t & 1) ^ 1] + AIDX(i0));
      const float4* evr = (const float4*)(evs[(t & 1) ^ 1] + AIDX(i0));
      float4 va[4], ve[4];
#pragma unroll
      for (int q = 0; q < 4; ++q) { va[q] = avr[q]; ve[q] = evr[q]; }

      // ================= viterbi: max + write (critical path first) ========
      v2f sv[16];
#pragma unroll
      for (int q = 0; q < 4; ++q) {
#pragma unroll
        for (int c = 0; c < 4; ++c) {
          float a = (c == 0) ? va[q].x : (c == 1) ? va[q].y
                  : (c == 2) ? va[q].z : va[q].w;
          sv[q * 4 + c] = (v2f){a, a} + tv[q * 4 + c];   // exact IEEE adds
        }
      }
      v2f m;
      {
        v2f m0 = __builtin_elementwise_max(sv[0], sv[1]);
        v2f m1 = __builtin_elementwise_max(sv[2], sv[3]);
        v2f m2 = __builtin_elementwise_max(sv[4], sv[5]);
        v2f m3 = __builtin_elementwise_max(sv[6], sv[7]);
        v2f m4 = __builtin_elementwise_max(sv[8], sv[9]);
        v2f m5 = __builtin_elementwise_max(sv[10], sv[11]);
        v2f m6 = __builtin_elementwise_max(sv[12], sv[13]);
        v2f m7 = __builtin_elementwise_max(sv[14], sv[15]);
        m0 = __builtin_elementwise_max(m0, m1);
        m2 = __builtin_elementwise_max(m2, m3);
        m4 = __builtin_elementwise_max(m4, m5);
        m6 = __builtin_elementwise_max(m6, m7);
        m0 = __builtin_elementwise_max(m0, m2);
        m4 = __builtin_elementwise_max(m4, m6);
        m = __builtin_elementwise_max(m0, m4);
      }
      {
        v2f o;
        o.x = dpp_f<0xB1>(m.x); o.y = dpp_f<0xB1>(m.y);
        m = __builtin_elementwise_max(m, o);
        o.x = dpp_f<0x4E>(m.x); o.y = dpp_f<0x4E>(m.y);
        m = __builtin_elementwise_max(m, o);
        o.x = dpp_f<0x141>(m.x); o.y = dpp_f<0x141>(m.y);
        m = __builtin_elementwise_max(m, o);
      }
      v2f em2 = emC[s];
      if (rg == 0)
        *(v2f*)(av[t & 1] + AIDX(j0)) = m + em2;

      // ================= forward: sum-product + write ======================
      v2f S2 = {0.0f, 0.0f};
#pragma unroll
      for (int q = 0; q < 4; ++q) {
#pragma unroll
        for (int c = 0; c < 4; ++c) {
          float e = (c == 0) ? ve[q].x : (c == 1) ? ve[q].y
                  : (c == 2) ? ve[q].z : ve[q].w;
          S2 += (v2f){e, e} * tw[q * 4 + c];   // pk_fma
        }
      }
      {
        v2f o;
        o.x = dpp_f<0xB1>(S2.x); o.y = dpp_f<0xB1>(S2.y); S2 += o;
        o.x = dpp_f<0x4E>(S2.x); o.y = dpp_f<0x4E>(S2.y); S2 += o;
        o.x = dpp_f<0x141>(S2.x); o.y = dpp_f<0x141>(S2.y); S2 += o;
      }
      float evn0 = S2.x * __expf(em2.x);
      float evn1 = S2.y * __expf(em2.y);
      if (s == 0) { evn0 *= r; evn1 *= r; }
      if (rg == 0)
        *(v2f*)(evs[t & 1] + AIDX(j0)) = (v2f){evn0, evn1};
      if (s == 3) {
        float wm = fmaxf(evn0, evn1);
        wm = fmaxf(wm, dpp_f<0x140>(wm));   // xor8 (values 8-uniform)
        wm = fmaxf(wm, swz16_f(wm));        // xor16
        if ((tid & 31) == 0) wmax[tid >> 5] = wm;
      }

      // ============ viterbi argmax recovery (off the alpha chain) ==========
      int ai0 = 0xFFFF, ai1 = 0xFFFF;
#pragma unroll
      for (int i = 15; i >= 0; --i) {
        ai0 = (sv[i].x == m.x) ? (i0 + i) : ai0;
        ai1 = (sv[i].y == m.y) ? (i0 + i) : ai1;
      }
      int aip = ai0 | (ai1 << 16);
      aip = pkminu16(aip, dpp_i<0xB1>(aip));
      aip = pkminu16(aip, dpp_i<0x4E>(aip));
      aip = pkminu16(aip, dpp_i<0x141>(aip));
      unsigned int pk = ((unsigned int)aip & 0xFFu) |
                        (((unsigned int)aip >> 8) & 0xFF00u);
      unsigned int sh = pk << ((s & 1) * 16);
      if (s < 2) w0p |= sh; else w1p |= sh;
      BARRIER_LGKM();
    }
    pw0 = w0p; pw1 = w1p; pend_c = (tc - 1) >> 2;
#pragma unroll
    for (int s = 0; s < 4; ++s) emC[s] = emN[s];
  }
  if (pend_c >= 0 && rg == 1) {
    *(uint2*)(bp + (((b << 7) + pend_c) << 9) + (cg << 3)) =
        make_uint2(pw0, pw1);
  }

  // ===================== tails (both paths) =====================
  const float* avf = av[(L - 1) & 1];
  const float* evf = evs[(L - 1) & 1];

  // viterbi final argmax across K
  {
    float v = (tid < KK) ? avf[AIDX(tid)] : -3.4e38f;
    int idx = (tid < KK) ? tid : KK;
#pragma unroll
    for (int mm = 1; mm < 64; mm <<= 1) {
      float ov = __shfl_xor(v, mm);
      int oi = __shfl_xor(idx, mm);
      if (ov > v || (ov == v && oi < idx)) { v = ov; idx = oi; }
    }
    if ((tid & 63) == 0) { rv[tid >> 6] = v; ri[tid >> 6] = idx; }
  }
  // forward final sum across K
  {
    float ssum = (tid < KK) ? evf[AIDX(tid)] : 0.0f;
#pragma unroll
    for (int mm = 1; mm < 64; mm <<= 1) ssum += __shfl_xor(ssum, mm);
    if ((tid & 63) == 0) rs[tid >> 6] = ssum;
  }
  // gold-path score
  {
    float sc = 0.0f;
    for (int tt2 = tid; tt2 < L; tt2 += 512) {
      int lab = labels[b * TT + tt2];
      sc += logits[(b * TT + tt2) * KK + lab];
      if (tt2 >= 1) sc += trans[labels[b * TT + tt2 - 1] * KK + lab];
    }
#pragma unroll
    for (int mm = 1; mm < 64; mm <<= 1) sc += __shfl_xor(sc, mm);
    if ((tid & 63) == 0) rsc[tid >> 6] = sc;
  }
  __syncthreads();
  if (tid == 0) {
    float bv = rv[0]; int bi = ri[0];
    float es = rs[0]; float scf = rsc[0];
#pragma unroll
    for (int w = 1; w < 8; ++w) {
      if (rv[w] > bv || (rv[w] == bv && ri[w] < bi)) { bv = rv[w]; bi = ri[w]; }
      es += rs[w]; scf += rsc[w];
    }
    last_s = bi;
    negll[b] = (Cln + logf(es)) - scf;
  }
  __syncthreads();
  const int last = last_s;
  if (tid >= L - 1 && tid < TT) tags[tid] = (unsigned char)last;
  __syncthreads();

  if (tid < 64 && L >= 2) {
    const uint2* bpv = (const uint2*)bp;
    int tag = last;
    int cTop = (L - 2) >> 2;
    uint2 q = bpv[(((b << 7) + cTop) << 6) + tid];
    for (int c = cTop; c >= 0; --c) {
      uint2 qn;
      if (c > 0) qn = bpv[(((b << 7) + (c - 1)) << 6) + tid];
      int sHi = (L - 2) - 4 * c; if (sHi > 3) sHi = 3;
#pragma unroll
      for (int s = 3; s >= 0; --s) {
        if (s <= sHi) {
          int word = (s < 2) ? (int)q.x : (int)q.y;
          unsigned int w = (unsigned int)__shfl(word, tag >> 1);
          tag = (int)((w >> ((((s & 1) << 1) | (tag & 1)) << 3)) & 255u);
          if (tid == 0) tags[4 * c + s] = (unsigned char)tag;
        }
      }
      q = qn;
    }
  }
  __syncthreads();
  pred_out[b * TT + tid] = (float)tags[tid];
}

__global__ void crf_loss_reduce(const float* __restrict__ negll, float* __restrict__ out) {
  int tid = threadIdx.x;
  float v = negll[tid];
#pragma unroll
  for (int m = 1; m < 64; m <<= 1) v += __shfl_xor(v, m);
  __shared__ float p[4];
  if ((tid & 63) == 0) p[tid >> 6] = v;
  __syncthreads();
  if (tid == 0) out[0] = p[0] + p[1] + p[2] + p[3];
}

extern "C" void kernel_launch(void* const* d_in, const int* in_sizes, int n_in,
                              void* d_out, int out_size, void* d_ws, size_t ws_size,
                              hipStream_t stream) {
  const float* logits   = (const float*)d_in[0];
  const int*   labels   = (const int*)d_in[1];
  const int*   seq_lens = (const int*)d_in[2];
  const float* trans    = (const float*)d_in[3];
  float* out = (float*)d_out;

  float* negll = (float*)d_ws;                          // 256 floats
  unsigned char* bp = (unsigned char*)d_ws + 1024;      // B*128*64*8 = 16.8 MB

  crf_main<<<BB, 512, 0, stream>>>(logits, labels, seq_lens, trans,
                                   out + 1, negll, bp);
  crf_loss_reduce<<<1, 256, 0, stream>>>(negll, out);
}

// Round 3
// 583.653 us; speedup vs baseline: 1.0261x; 1.0261x over previous
//
#include <hip/hip_runtime.h>
#include <math.h>

#define BB 256
#define TT 512
#define KK 128
#define THR 256
#define AIDX(i) ((i) + (((i) >> 5) << 2))

typedef float v2f __attribute__((ext_vector_type(2)));
typedef unsigned short u16v2 __attribute__((ext_vector_type(2)));

template<int CTRL>
__device__ __forceinline__ int dpp_i(int x) {
  return __builtin_amdgcn_update_dpp(x, x, CTRL, 0xF, 0xF, true);
}
template<int CTRL>
__device__ __forceinline__ float dpp_f(float x) {
  return __int_as_float(dpp_i<CTRL>(__float_as_int(x)));
}
__device__ __forceinline__ float swz16_f(float x) {
  return __int_as_float(__builtin_amdgcn_ds_swizzle(__float_as_int(x), 0x401F));
}
__device__ __forceinline__ int pkminu16(int a, int b) {
  u16v2 av = *(u16v2*)&a, bv = *(u16v2*)&b;
  u16v2 r = __builtin_elementwise_min(av, bv);
  return *(int*)&r;
}
// barrier that drains LDS only (not vmcnt) — keeps prefetch loads in flight
#define BARRIER_LGKM() asm volatile("s_waitcnt lgkmcnt(0)\ns_barrier" ::: "memory")

// Two blocks per sequence (vit, fwd) as in the 438us baseline, but 256 threads
// per block: thread = 2 cols x 32 rows, rg = tid&3 lives IN THE QUAD.
// - barrier group = 4 waves (was 8): tests the "C scales with group size" model
// - cross-lane reduce = 2 quad_perm DPP levels (was 3 row-level)
// - argmax scan = 4 parallel 8-deep chains + min-combine (exact same result)

__global__ __launch_bounds__(THR, 2) void crf_main(
    const float* __restrict__ logits,     // [B,T,K]
    const int* __restrict__ labels,       // [B,T]
    const int* __restrict__ seq_lens,     // [B]
    const float* __restrict__ trans,      // [K,K]
    float* __restrict__ pred_out,         // [B,T] as float (d_out+1)
    float* __restrict__ negll,            // [B] in ws
    unsigned char* __restrict__ bp)       // [B][128 chunk][64 cg][8B] in ws
{
  const int tid = threadIdx.x;
  const int cg = tid >> 2, rg = tid & 3;     // 64 col-groups x 4 row-groups
  const int j0 = cg * 2, i0 = rg * 32;

  if (blockIdx.x < BB) {
    // ================= VITERBI PATH =================
    const int b = blockIdx.x;
    const int L = seq_lens[b];
    __shared__ __align__(16) float av[2][144];
    __shared__ unsigned char tags[TT];
    __shared__ float rv[4]; __shared__ int ri[4];
    __shared__ int last_s;

    v2f tv[32];
#pragma unroll
    for (int ii = 0; ii < 32; ++ii)
      tv[ii] = *(const v2f*)&trans[(i0 + ii) * KK + j0];

    if (tid < KK) av[0][AIDX(tid)] = logits[(b * TT) * KK + tid];

    v2f emC[4], emN[4];
#pragma unroll
    for (int s = 0; s < 4; ++s) {
      int t2 = 1 + s; if (t2 > L - 1) t2 = (L > 1) ? (L - 1) : 0;
      emC[s] = *(const v2f*)&logits[(b * TT + t2) * KK + j0];
    }
    __syncthreads();

    unsigned int pw0 = 0, pw1 = 0; int pend_c = -1;

    for (int tc = 1; tc < L; tc += 4) {
#pragma unroll
      for (int s = 0; s < 4; ++s) {
        int t2 = tc + 4 + s; if (t2 > L - 1) t2 = L - 1;
        emN[s] = *(const v2f*)&logits[(b * TT + t2) * KK + j0];
      }
      if (pend_c >= 0 && rg == 1) {
        *(uint2*)(bp + (((b << 7) + pend_c) << 9) + (cg << 3)) =
            make_uint2(pw0, pw1);
      }
      unsigned int w0p = 0, w1p = 0;
#pragma unroll
      for (int s = 0; s < 4; ++s) {
        const int t = tc + s;
        if (t >= L) break;
        const float4* avr = (const float4*)(av[(t & 1) ^ 1] + AIDX(i0));
        v2f sv[32];
#pragma unroll
        for (int q = 0; q < 8; ++q) {
          float4 a4 = avr[q];
#pragma unroll
          for (int c = 0; c < 4; ++c) {
            float a = (c == 0) ? a4.x : (c == 1) ? a4.y : (c == 2) ? a4.z : a4.w;
            sv[q * 4 + c] = (v2f){a, a} + tv[q * 4 + c];   // exact IEEE adds
          }
        }
        // in-thread max tree over 32 (exact; max order-insensitive)
        v2f m;
        {
          v2f t0[16];
#pragma unroll
          for (int k = 0; k < 16; ++k)
            t0[k] = __builtin_elementwise_max(sv[2 * k], sv[2 * k + 1]);
#pragma unroll
          for (int k = 0; k < 8; ++k)
            t0[k] = __builtin_elementwise_max(t0[2 * k], t0[2 * k + 1]);
#pragma unroll
          for (int k = 0; k < 4; ++k)
            t0[k] = __builtin_elementwise_max(t0[2 * k], t0[2 * k + 1]);
#pragma unroll
          for (int k = 0; k < 2; ++k)
            t0[k] = __builtin_elementwise_max(t0[2 * k], t0[2 * k + 1]);
          m = __builtin_elementwise_max(t0[0], t0[1]);
        }
        // global max across the 4 row-groups: quad-local DPP (xor1, xor2)
        {
          v2f o;
          o.x = dpp_f<0xB1>(m.x); o.y = dpp_f<0xB1>(m.y);
          m = __builtin_elementwise_max(m, o);
          o.x = dpp_f<0x4E>(m.x); o.y = dpp_f<0x4E>(m.y);
          m = __builtin_elementwise_max(m, o);
        }
        v2f em2 = emC[s];
        if (rg == 0)
          *(v2f*)(av[t & 1] + AIDX(j0)) = m + em2;

        // first-index recovery: 4 parallel downward 8-chains, min-combine
        int a0h[4], a1h[4];
#pragma unroll
        for (int h = 0; h < 4; ++h) { a0h[h] = 0xFFFF; a1h[h] = 0xFFFF; }
#pragma unroll
        for (int i = 7; i >= 0; --i) {
#pragma unroll
          for (int h = 0; h < 4; ++h) {
            int idx = i0 + h * 8 + i;
            a0h[h] = (sv[h * 8 + i].x == m.x) ? idx : a0h[h];
            a1h[h] = (sv[h * 8 + i].y == m.y) ? idx : a1h[h];
          }
        }
        int ai0 = min(min(a0h[0], a0h[1]), min(a0h[2], a0h[3]));
        int ai1 = min(min(a1h[0], a1h[1]), min(a1h[2], a1h[3]));
        int aip = ai0 | (ai1 << 16);
        aip = pkminu16(aip, dpp_i<0xB1>(aip));
        aip = pkminu16(aip, dpp_i<0x4E>(aip));
        unsigned int pk = ((unsigned int)aip & 0xFFu) |
                          (((unsigned int)aip >> 8) & 0xFF00u);
        unsigned int sh = pk << ((s & 1) * 16);
        if (s < 2) w0p |= sh; else w1p |= sh;
        BARRIER_LGKM();
      }
      pw0 = w0p; pw1 = w1p; pend_c = (tc - 1) >> 2;
#pragma unroll
      for (int s = 0; s < 4; ++s) emC[s] = emN[s];
    }
    if (pend_c >= 0 && rg == 1) {
      *(uint2*)(bp + (((b << 7) + pend_c) << 9) + (cg << 3)) =
          make_uint2(pw0, pw1);
    }

    const float* avf = av[(L - 1) & 1];
    {
      float v = (tid < KK) ? avf[AIDX(tid)] : -3.4e38f;
      int idx = (tid < KK) ? tid : KK;
#pragma unroll
      for (int mm = 1; mm < 64; mm <<= 1) {
        float ov = __shfl_xor(v, mm);
        int oi = __shfl_xor(idx, mm);
        if (ov > v || (ov == v && oi < idx)) { v = ov; idx = oi; }
      }
      if ((tid & 63) == 0) { rv[tid >> 6] = v; ri[tid >> 6] = idx; }
    }
    __syncthreads();
    if (tid == 0) {
      float bv = rv[0]; int bi = ri[0];
#pragma unroll
      for (int w = 1; w < 4; ++w)
        if (rv[w] > bv || (rv[w] == bv && ri[w] < bi)) { bv = rv[w]; bi = ri[w]; }
      last_s = bi;
    }
    __syncthreads();
    const int last = last_s;
#pragma unroll
    for (int tt = tid; tt < TT; tt += THR)
      if (tt >= L - 1) tags[tt] = (unsigned char)last;
    __syncthreads();

    if (tid < 64 && L >= 2) {
      const uint2* bpv = (const uint2*)bp;
      int tag = last;
      int cTop = (L - 2) >> 2;
      uint2 q = bpv[(((b << 7) + cTop) << 6) + tid];
      for (int c = cTop; c >= 0; --c) {
        uint2 qn;
        if (c > 0) qn = bpv[(((b << 7) + (c - 1)) << 6) + tid];
        int sHi = (L - 2) - 4 * c; if (sHi > 3) sHi = 3;
#pragma unroll
        for (int s = 3; s >= 0; --s) {
          if (s <= sHi) {
            int word = (s < 2) ? (int)q.x : (int)q.y;
            unsigned int w = (unsigned int)__shfl(word, tag >> 1);
            tag = (int)((w >> ((((s & 1) << 1) | (tag & 1)) << 3)) & 255u);
            if (tid == 0) tags[4 * c + s] = (unsigned char)tag;
          }
        }
        q = qn;
      }
    }
    __syncthreads();
#pragma unroll
    for (int tt = tid; tt < TT; tt += THR)
      pred_out[b * TT + tt] = (float)tags[tt];

  } else {
    // ================= FORWARD (log-norm) PATH =================
    const int b = blockIdx.x - BB;
    const int L = seq_lens[b];
    __shared__ __align__(16) float ev[2][144];
    __shared__ __align__(16) float wmax[8];
    __shared__ float rs[4]; __shared__ float rsc[4];

    v2f tw[32];
#pragma unroll
    for (int ii = 0; ii < 32; ++ii) {
      v2f tr = *(const v2f*)&trans[(i0 + ii) * KK + j0];
      tw[ii].x = __expf(tr.x);
      tw[ii].y = __expf(tr.y);
    }
    if (tid < KK) ev[0][AIDX(tid)] = __expf(logits[(b * TT) * KK + tid]);
    if (tid < 8) wmax[tid] = 1.0f;

    v2f emC[4], emN[4];
#pragma unroll
    for (int s = 0; s < 4; ++s) {
      int t2 = 1 + s; if (t2 > L - 1) t2 = (L > 1) ? (L - 1) : 0;
      emC[s] = *(const v2f*)&logits[(b * TT + t2) * KK + j0];
    }
    __syncthreads();

    float Cln = 0.0f;
    for (int tc = 1; tc < L; tc += 4) {
#pragma unroll
      for (int s = 0; s < 4; ++s) {
        int t2 = tc + 4 + s; if (t2 > L - 1) t2 = L - 1;
        emN[s] = *(const v2f*)&logits[(b * TT + t2) * KK + j0];
      }
      // renorm factor (exact pow2), once per 4-step chunk
      float r;
      {
        float4 q0 = *(const float4*)&wmax[0];
        float4 q1 = *(const float4*)&wmax[4];
        float U = fmaxf(fmaxf(fmaxf(q0.x, q0.y), fmaxf(q0.z, q0.w)),
                        fmaxf(fmaxf(q1.x, q1.y), fmaxf(q1.z, q1.w)));
        int ex = (__float_as_int(U) >> 23) & 255;
        r = __int_as_float((254 - ex) << 23);
        Cln += (float)(ex - 127) * 0.6931471805599453f;
      }
#pragma unroll
      for (int s = 0; s < 4; ++s) {
        const int t = tc + s;
        if (t >= L) break;
        const float4* evr = (const float4*)(ev[(t & 1) ^ 1] + AIDX(i0));
        // hoist emission exps into the LDS-read shadow
        v2f em2 = emC[s];
        float ee0 = __expf(em2.x), ee1 = __expf(em2.y);
        v2f S2 = {0.0f, 0.0f};
#pragma unroll
        for (int q = 0; q < 8; ++q) {
          float4 e4 = evr[q];
#pragma unroll
          for (int c = 0; c < 4; ++c) {
            float e = (c == 0) ? e4.x : (c == 1) ? e4.y : (c == 2) ? e4.z : e4.w;
            S2 += (v2f){e, e} * tw[q * 4 + c];   // pk_fma
          }
        }
        {
          v2f o;
          o.x = dpp_f<0xB1>(S2.x); o.y = dpp_f<0xB1>(S2.y); S2 += o;
          o.x = dpp_f<0x4E>(S2.x); o.y = dpp_f<0x4E>(S2.y); S2 += o;
        }
        float evn0 = S2.x * ee0;
        float evn1 = S2.y * ee1;
        if (s == 0) { evn0 *= r; evn1 *= r; }
        if (rg == 0)
          *(v2f*)(ev[t & 1] + AIDX(j0)) = (v2f){evn0, evn1};
        if (s == 3) {
          float wm = fmaxf(evn0, evn1);          // quad-uniform already
          wm = fmaxf(wm, dpp_f<0x141>(wm));      // xor4 (quad-uniform)
          wm = fmaxf(wm, dpp_f<0x140>(wm));      // xor8 (8-uniform)
          wm = fmaxf(wm, swz16_f(wm));           // xor16
          if ((tid & 31) == 0) wmax[tid >> 5] = wm;
        }
        BARRIER_LGKM();
      }
#pragma unroll
      for (int s = 0; s < 4; ++s) emC[s] = emN[s];
    }

    const float* evf = ev[(L - 1) & 1];
    {
      float ssum = (tid < KK) ? evf[AIDX(tid)] : 0.0f;
#pragma unroll
      for (int mm = 1; mm < 64; mm <<= 1) ssum += __shfl_xor(ssum, mm);
      if ((tid & 63) == 0) rs[tid >> 6] = ssum;
    }
    float sc = 0.0f;
    for (int tt2 = tid; tt2 < L; tt2 += THR) {
      int lab = labels[b * TT + tt2];
      sc += logits[(b * TT + tt2) * KK + lab];
      if (tt2 >= 1) sc += trans[labels[b * TT + tt2 - 1] * KK + lab];
    }
#pragma unroll
    for (int mm = 1; mm < 64; mm <<= 1) sc += __shfl_xor(sc, mm);
    if ((tid & 63) == 0) rsc[tid >> 6] = sc;
    __syncthreads();
    if (tid == 0) {
      float es = rs[0]; float scf = rsc[0];
#pragma unroll
      for (int w = 1; w < 4; ++w) { es += rs[w]; scf += rsc[w]; }
      negll[b] = (Cln + logf(es)) - scf;
    }
  }
}

__global__ void crf_loss_reduce(const float* __restrict__ negll, float* __restrict__ out) {
  int tid = threadIdx.x;
  float v = negll[tid];
#pragma unroll
  for (int m = 1; m < 64; m <<= 1) v += __shfl_xor(v, m);
  __shared__ float p[4];
  if ((tid & 63) == 0) p[tid >> 6] = v;
  __syncthreads();
  if (tid == 0) out[0] = p[0] + p[1] + p[2] + p[3];
}

extern "C" void kernel_launch(void* const* d_in, const int* in_sizes, int n_in,
                              void* d_out, int out_size, void* d_ws, size_t ws_size,
                              hipStream_t stream) {
  const float* logits   = (const float*)d_in[0];
  const int*   labels   = (const int*)d_in[1];
  const int*   seq_lens = (const int*)d_in[2];
  const float* trans    = (const float*)d_in[3];
  float* out = (float*)d_out;

  float* negll = (float*)d_ws;                          // 256 floats
  unsigned char* bp = (unsigned char*)d_ws + 1024;      // B*128*64*8 = 16.8 MB

  crf_main<<<2 * BB, THR, 0, stream>>>(logits, labels, seq_lens, trans,
                                       out + 1, negll, bp);
  crf_loss_reduce<<<1, 256, 0, stream>>>(negll, out);
}